// Round 2
// baseline (189.686 us; speedup 1.0000x reference)
//
#include <hip/hip_runtime.h>
#include <math.h>

// LSTM_55344948576591 — two-kernel implementation.
// B=256, T=32, CNN_DIM=512, HW=14 (196 elems/channel), HID=8, V=37, G=4*HID=32.
//
// Kernel 1 (pool_kernel): the HBM-bound adaptive avg-pool (103 MB read).
//   grid = B*4 = 1024 blocks x 256 thr -> 4 blocks/CU, 16 waves/CU.
//   Each wave: 32 channels, 8-deep float4 load double-buffer (prefetch next
//   8 channels while shuffle-reducing current 8). Fixes R1's latency-bound
//   pooling (1 block/CU, 877 GB/s, VALUBusy 7.5%).
// Kernel 2 (lstm_rest): phases B-F of the R1 kernel, one block per batch.

#define BDIM 512

__device__ __forceinline__ float wave_reduce_sum(float v) {
#pragma unroll
    for (int off = 32; off; off >>= 1) v += __shfl_down(v, off, 64);
    return v;
}

__device__ __forceinline__ float sigf(float x) { return 1.0f / (1.0f + __expf(-x)); }
__device__ __forceinline__ float tanhfast(float x) { return 1.0f - 2.0f / (__expf(2.0f * x) + 1.0f); }

// ---------------------------------------------------------------------------
// Kernel 1: pooling. grid = B*4, block = 256. Block (b,q) -> channels q*128..+127.
// ---------------------------------------------------------------------------
__global__ __launch_bounds__(256, 4) void pool_kernel(
    const float* __restrict__ features, float* __restrict__ pooled /* [B][C] */)
{
    constexpr int NPIX = 196, C = 512;
    const int b    = blockIdx.x >> 2;
    const int q    = blockIdx.x & 3;
    const int lane = threadIdx.x & 63;
    const int w    = threadIdx.x >> 6;              // 0..3
    const int c0   = q * 128 + w * 32;              // this wave: channels c0..c0+31
    const float* featB = features + (size_t)b * C * NPIX;
    const int li = (lane < 49) ? lane : 0;          // 196 floats = 49 float4/channel

    float4 buf[8];
#pragma unroll
    for (int u = 0; u < 8; ++u)
        buf[u] = ((const float4*)(featB + (c0 + u) * NPIX))[li];

    for (int grp = 0; grp < 4; ++grp) {
        float s[8];
#pragma unroll
        for (int u = 0; u < 8; ++u) {
            const float4 v = buf[u];
            s[u] = (lane < 49) ? (v.x + v.y) + (v.z + v.w) : 0.0f;
        }
        if (grp < 3) {
#pragma unroll
            for (int u = 0; u < 8; ++u)
                buf[u] = ((const float4*)(featB + (c0 + (grp + 1) * 8 + u) * NPIX))[li];
        }
#pragma unroll
        for (int u = 0; u < 8; ++u) {
            const float tot = wave_reduce_sum(s[u]);
            if (lane == 0)
                pooled[(size_t)b * C + c0 + grp * 8 + u] = tot * (1.0f / 196.0f);
        }
    }
}

// ---------------------------------------------------------------------------
// Kernel 2: everything after pooling. grid = B, block = 512.
// ---------------------------------------------------------------------------
__global__ __launch_bounds__(BDIM) void lstm_rest(
    const float* __restrict__ pooled_g, const float* __restrict__ captions,
    const float* __restrict__ W_ih, const float* __restrict__ b_ih,
    const float* __restrict__ W_hh, const float* __restrict__ b_hh,
    const float* __restrict__ W_in, const float* __restrict__ b_in,
    const float* __restrict__ W_out, const float* __restrict__ b_out,
    const int* __restrict__ isTraining, float* __restrict__ out)
{
    constexpr int T = 32, V = 37, HID = 8, C = 512, G = 32;

    __shared__ float pooled[C];
    __shared__ float xs[T * V];
    __shared__ float wih[G * V];
    __shared__ float xg[T * G];
    __shared__ float hist[T * HID];
    __shared__ float lg[T * V];
    __shared__ float bsum[G];
    __shared__ float inv_s[V];

    const int b    = blockIdx.x;
    const int tid  = threadIdx.x;
    const int lane = tid & 63;
    const int w    = tid >> 6;   // 0..7

    // Stage pooled + small tensors into LDS.
    pooled[tid] = pooled_g[(size_t)b * C + tid];
    for (int i = tid; i < G * V; i += BDIM) wih[i] = W_ih[i];
    for (int i = tid + V; i < T * V; i += BDIM) xs[i] = captions[(size_t)b * T * V + (i - V)];
    if (tid < G) bsum[tid] = b_ih[tid] + b_hh[tid];
    __syncthreads();

    // Phase B: x0 = pooled @ W_in.T + b_in
    for (int v = w; v < V; v += 8) {
        const float* wr = W_in + (size_t)v * C;
        float p = 0.0f;
#pragma unroll
        for (int k = 0; k < 8; ++k) p += pooled[lane + 64 * k] * wr[lane + 64 * k];
        p = wave_reduce_sum(p);
        if (lane == 0) xs[v] = p + b_in[v];
    }
    __syncthreads();

    // Phase C: xg[t][j] = xs[t]@W_ih.T + (b_ih+b_hh)
    for (int e = tid; e < T * G; e += BDIM) {
        const int t = e >> 5, j = e & 31;
        const float* xr = xs + t * V;
        const float* wr = wih + j * V;
        float acc = bsum[j];
#pragma unroll
        for (int v = 0; v < V; ++v) acc += xr[v] * wr[v];
        xg[e] = acc;
    }
    __syncthreads();

    // Phase D: sequential recurrence (wave 0 only)
    const bool train = (isTraining[0] != 0);
    if (w == 0) {
        const int j = lane & 31;
        const int k8 = lane & 7;
        float whh_r[HID];
#pragma unroll
        for (int k = 0; k < HID; ++k) whh_r[k] = W_hh[j * HID + k];
        float wout_r[HID];
        float bout_r = 0.0f;
        if (lane < V) {
#pragma unroll
            for (int k = 0; k < HID; ++k) wout_r[k] = W_out[lane * HID + k];
            bout_r = b_out[lane];
        }
        float h = 0.0f, c = 0.0f;
        float prevout = 0.0f;

        for (int t = 0; t < T; ++t) {
            float gate;
            if (train || t == 0) {
                gate = xg[t * G + j];
            } else {
                float acc = bsum[j];
                const float* wr = wih + j * V;
#pragma unroll
                for (int v = 0; v < V; ++v) acc += __shfl(prevout, v, 64) * wr[v];
                gate = acc;
            }
#pragma unroll
            for (int k = 0; k < HID; ++k) gate += __shfl(h, k, 64) * whh_r[k];

            const int sec = lane >> 3;              // 0:i 1:f 2:g 3:o
            const float a = (sec == 2) ? tanhfast(gate) : sigf(gate);

            const float ig = __shfl(a, k8, 64);
            const float fg = __shfl(a, 8 + k8, 64);
            const float gg = __shfl(a, 16 + k8, 64);
            const float og = __shfl(a, 24 + k8, 64);
            c = fg * c + ig * gg;
            h = og * tanhfast(c);

            if (train) {
                if (lane < HID) hist[t * HID + lane] = h;
            } else {
                float o = bout_r;
#pragma unroll
                for (int k = 0; k < HID; ++k) o += __shfl(h, k, 64) * wout_r[k];
                if (lane < V) lg[t * V + lane] = o;
                prevout = o;
            }
        }
    }
    __syncthreads();

    // Phase E: logits (training path)
    if (train) {
        for (int e = tid; e < T * V; e += BDIM) {
            const int t = e / V, v = e - t * V;
            const float* hr = hist + t * HID;
            const float* wr = W_out + v * HID;
            float acc = b_out[v];
#pragma unroll
            for (int k = 0; k < HID; ++k) acc += hr[k] * wr[k];
            lg[e] = acc;
        }
    }
    __syncthreads();

    // Phase F: softmax over TIME axis
    if (tid < V) {
        float m = -1e30f;
#pragma unroll
        for (int t = 0; t < T; ++t) m = fmaxf(m, lg[t * V + tid]);
        float s = 0.0f;
#pragma unroll
        for (int t = 0; t < T; ++t) {
            const float e = __expf(lg[t * V + tid] - m);
            lg[t * V + tid] = e;
            s += e;
        }
        inv_s[tid] = 1.0f / s;
    }
    __syncthreads();

    float* outB = out + (size_t)b * T * V;
    for (int e = tid; e < T * V; e += BDIM) {
        const int t = e / V, v = e - t * V;
        outB[e] = lg[e] * inv_s[v];
    }
}

extern "C" void kernel_launch(void* const* d_in, const int* in_sizes, int n_in,
                              void* d_out, int out_size, void* d_ws, size_t ws_size,
                              hipStream_t stream) {
    const float* features = (const float*)d_in[0];
    const float* captions = (const float*)d_in[1];
    const float* W_ih     = (const float*)d_in[2];
    const float* b_ih     = (const float*)d_in[3];
    const float* W_hh     = (const float*)d_in[4];
    const float* b_hh     = (const float*)d_in[5];
    const float* W_in     = (const float*)d_in[6];
    const float* b_in     = (const float*)d_in[7];
    const float* W_out    = (const float*)d_in[8];
    const float* b_out    = (const float*)d_in[9];
    const int*   isTrain  = (const int*)d_in[10];
    float* out = (float*)d_out;

    float* pooled = (float*)d_ws;   // [B][C] = 256*512 floats = 512 KB

    pool_kernel<<<256 * 4, 256, 0, stream>>>(features, pooled);
    lstm_rest<<<256, BDIM, 0, stream>>>(pooled, captions, W_ih, b_ih, W_hh, b_hh,
                                        W_in, b_in, W_out, b_out, isTrain, out);
}

// Round 3
// 185.171 us; speedup vs baseline: 1.0244x; 1.0244x over previous
//
#include <hip/hip_runtime.h>
#include <math.h>

// LSTM_55344948576591 — two-kernel implementation, R3.
// B=256, T=32, CNN_DIM=512, HW=14 (196 elems/channel), HID=8, V=37, G=4*HID=32.
//
// R3 change: pool_kernel rebuilt as a fill-style streamer. R2's 8-deep
// per-wave prefetch + reduce chain still ran ~50+ us (in-order vmcnt drain
// coupled to a ~130-instr reduce chain per group). New structure: one wave
// per channel, ONE masked float4 load per wave, 6-step shuffle reduce, one
// store, exit. Concurrency = 32 short-lived waves/CU streaming over 8192
// blocks (the harness fill sustains 6.9 TB/s with exactly this shape).
// lstm_rest unchanged from R2 (proven correct, est. 10-20 us).

#define BDIM 512

__device__ __forceinline__ float wave_reduce_sum(float v) {
#pragma unroll
    for (int off = 32; off; off >>= 1) v += __shfl_down(v, off, 64);
    return v;
}

__device__ __forceinline__ float sigf(float x) { return 1.0f / (1.0f + __expf(-x)); }
__device__ __forceinline__ float tanhfast(float x) { return 1.0f - 2.0f / (__expf(2.0f * x) + 1.0f); }

// ---------------------------------------------------------------------------
// Kernel 1: pooling. grid = B*C/16 = 8192 blocks x 1024 thr (16 waves/block).
// Wave handles exactly one channel: 49 lanes load one float4 each (784 B
// contiguous; consecutive waves cover consecutive 784-B runs -> the whole
// grid is one linear sweep of the 103 MB tensor). features layout [B][C][196]
// is flat, so wave id == channel id == pooled index.
// ---------------------------------------------------------------------------
__global__ void pool_kernel(
    const float* __restrict__ features, float* __restrict__ pooled /* [B*C] */)
{
    constexpr int NPIX = 196;
    const int wid  = (blockIdx.x << 4) + (threadIdx.x >> 6);  // global wave = channel
    const int lane = threadIdx.x & 63;
    const float* base = features + (size_t)wid * NPIX;

    float s = 0.0f;
    if (lane < 49) {                       // exec-masked load, no branch body
        const float4 v = ((const float4*)base)[lane];
        s = (v.x + v.y) + (v.z + v.w);
    }
    s = wave_reduce_sum(s);
    if (lane == 0) pooled[wid] = s * (1.0f / 196.0f);
}

// ---------------------------------------------------------------------------
// Kernel 2: everything after pooling. grid = B, block = 512. (R2, unchanged)
// ---------------------------------------------------------------------------
__global__ __launch_bounds__(BDIM) void lstm_rest(
    const float* __restrict__ pooled_g, const float* __restrict__ captions,
    const float* __restrict__ W_ih, const float* __restrict__ b_ih,
    const float* __restrict__ W_hh, const float* __restrict__ b_hh,
    const float* __restrict__ W_in, const float* __restrict__ b_in,
    const float* __restrict__ W_out, const float* __restrict__ b_out,
    const int* __restrict__ isTraining, float* __restrict__ out)
{
    constexpr int T = 32, V = 37, HID = 8, C = 512, G = 32;

    __shared__ float pooled[C];
    __shared__ float xs[T * V];
    __shared__ float wih[G * V];
    __shared__ float xg[T * G];
    __shared__ float hist[T * HID];
    __shared__ float lg[T * V];
    __shared__ float bsum[G];
    __shared__ float inv_s[V];

    const int b    = blockIdx.x;
    const int tid  = threadIdx.x;
    const int lane = tid & 63;
    const int w    = tid >> 6;   // 0..7

    pooled[tid] = pooled_g[(size_t)b * C + tid];
    for (int i = tid; i < G * V; i += BDIM) wih[i] = W_ih[i];
    for (int i = tid + V; i < T * V; i += BDIM) xs[i] = captions[(size_t)b * T * V + (i - V)];
    if (tid < G) bsum[tid] = b_ih[tid] + b_hh[tid];
    __syncthreads();

    // Phase B: x0 = pooled @ W_in.T + b_in
    for (int v = w; v < V; v += 8) {
        const float* wr = W_in + (size_t)v * C;
        float p = 0.0f;
#pragma unroll
        for (int k = 0; k < 8; ++k) p += pooled[lane + 64 * k] * wr[lane + 64 * k];
        p = wave_reduce_sum(p);
        if (lane == 0) xs[v] = p + b_in[v];
    }
    __syncthreads();

    // Phase C: xg[t][j] = xs[t]@W_ih.T + (b_ih+b_hh)
    for (int e = tid; e < T * G; e += BDIM) {
        const int t = e >> 5, j = e & 31;
        const float* xr = xs + t * V;
        const float* wr = wih + j * V;
        float acc = bsum[j];
#pragma unroll
        for (int v = 0; v < V; ++v) acc += xr[v] * wr[v];
        xg[e] = acc;
    }
    __syncthreads();

    // Phase D: sequential recurrence (wave 0 only)
    const bool train = (isTraining[0] != 0);
    if (w == 0) {
        const int j = lane & 31;
        const int k8 = lane & 7;
        float whh_r[HID];
#pragma unroll
        for (int k = 0; k < HID; ++k) whh_r[k] = W_hh[j * HID + k];
        float wout_r[HID];
        float bout_r = 0.0f;
        if (lane < V) {
#pragma unroll
            for (int k = 0; k < HID; ++k) wout_r[k] = W_out[lane * HID + k];
            bout_r = b_out[lane];
        }
        float h = 0.0f, c = 0.0f;
        float prevout = 0.0f;

        for (int t = 0; t < T; ++t) {
            float gate;
            if (train || t == 0) {
                gate = xg[t * G + j];
            } else {
                float acc = bsum[j];
                const float* wr = wih + j * V;
#pragma unroll
                for (int v = 0; v < V; ++v) acc += __shfl(prevout, v, 64) * wr[v];
                gate = acc;
            }
#pragma unroll
            for (int k = 0; k < HID; ++k) gate += __shfl(h, k, 64) * whh_r[k];

            const int sec = lane >> 3;              // 0:i 1:f 2:g 3:o
            const float a = (sec == 2) ? tanhfast(gate) : sigf(gate);

            const float ig = __shfl(a, k8, 64);
            const float fg = __shfl(a, 8 + k8, 64);
            const float gg = __shfl(a, 16 + k8, 64);
            const float og = __shfl(a, 24 + k8, 64);
            c = fg * c + ig * gg;
            h = og * tanhfast(c);

            if (train) {
                if (lane < HID) hist[t * HID + lane] = h;
            } else {
                float o = bout_r;
#pragma unroll
                for (int k = 0; k < HID; ++k) o += __shfl(h, k, 64) * wout_r[k];
                if (lane < V) lg[t * V + lane] = o;
                prevout = o;
            }
        }
    }
    __syncthreads();

    // Phase E: logits (training path)
    if (train) {
        for (int e = tid; e < T * V; e += BDIM) {
            const int t = e / V, v = e - t * V;
            const float* hr = hist + t * HID;
            const float* wr = W_out + v * HID;
            float acc = b_out[v];
#pragma unroll
            for (int k = 0; k < HID; ++k) acc += hr[k] * wr[k];
            lg[e] = acc;
        }
    }
    __syncthreads();

    // Phase F: softmax over TIME axis
    if (tid < V) {
        float m = -1e30f;
#pragma unroll
        for (int t = 0; t < T; ++t) m = fmaxf(m, lg[t * V + tid]);
        float s = 0.0f;
#pragma unroll
        for (int t = 0; t < T; ++t) {
            const float e = __expf(lg[t * V + tid] - m);
            lg[t * V + tid] = e;
            s += e;
        }
        inv_s[tid] = 1.0f / s;
    }
    __syncthreads();

    float* outB = out + (size_t)b * T * V;
    for (int e = tid; e < T * V; e += BDIM) {
        const int t = e / V, v = e - t * V;
        outB[e] = lg[e] * inv_s[v];
    }
}

extern "C" void kernel_launch(void* const* d_in, const int* in_sizes, int n_in,
                              void* d_out, int out_size, void* d_ws, size_t ws_size,
                              hipStream_t stream) {
    const float* features = (const float*)d_in[0];
    const float* captions = (const float*)d_in[1];
    const float* W_ih     = (const float*)d_in[2];
    const float* b_ih     = (const float*)d_in[3];
    const float* W_hh     = (const float*)d_in[4];
    const float* b_hh     = (const float*)d_in[5];
    const float* W_in     = (const float*)d_in[6];
    const float* b_in     = (const float*)d_in[7];
    const float* W_out    = (const float*)d_in[8];
    const float* b_out    = (const float*)d_in[9];
    const int*   isTrain  = (const int*)d_in[10];
    float* out = (float*)d_out;

    float* pooled = (float*)d_ws;   // [B*C] = 131072 floats = 512 KB

    // 8192 blocks x 1024 threads: 16 waves/block, one channel per wave.
    pool_kernel<<<8192, 1024, 0, stream>>>(features, pooled);
    lstm_rest<<<256, BDIM, 0, stream>>>(pooled, captions, W_ih, b_ih, W_hh, b_hh,
                                        W_in, b_in, W_out, b_out, isTrain, out);
}